// Round 3
// baseline (352.234 us; speedup 1.0000x reference)
//
#include <hip/hip_runtime.h>
#include <math.h>

#define NSEG 7320
#define NLON 120
#define HIDN 128

// ---------------------------------------------------------------------------
// K1: grp 0-3: q (pre-scaled 1/sqrt(DH)) n-major; 4-7: k n-major; 8-11: v
// n-major; grp 12: raw-x transpose to n-major (K2 residual); grp 13-14: meta
// {hi*120, dl, qw bits} + per-lat-row CSR offsets (folded former K0).
// All via LN0 except grp 12-14.
// ---------------------------------------------------------------------------
__global__ __launch_bounds__(64) void k1_ln_qkv(
    const float* __restrict__ x,  const float* __restrict__ wq,
    const float* __restrict__ wk, const float* __restrict__ wv,
    const float* __restrict__ g,  const float* __restrict__ b,
    const int* __restrict__ out_idx, const int* __restrict__ in_idx,
    const float* __restrict__ qw, int E,
    float* __restrict__ q_nm, float* __restrict__ k_nm,
    float* __restrict__ v_nm, float* __restrict__ x_nm,
    int* __restrict__ row_start, int4* __restrict__ meta)
{
    __shared__ __align__(16) float sm[64 * 20];
    const int lane = threadIdx.x;
    const int tile = blockIdx.x;
    const int grp  = blockIdx.y;

    if (grp >= 13) {                       // meta + row_start build
        int e = ((grp - 13) * 115 + tile) * 64 + lane;
        if (e >= E) return;
        int ho = out_idx[e * NLON] / NLON;
        if (e == 0) {
            row_start[ho] = 0;
        } else {
            int hp = out_idx[(e - 1) * NLON] / NLON;
            if (hp != ho) row_start[ho] = e;
        }
        if (e == E - 1) row_start[ho + 1] = E;
        int i0 = in_idx[e * NLON];         // wo = 0 column: hi*120 + dl
        int hi = i0 / NLON;
        int dl = i0 - hi * NLON;
        meta[e] = make_int4(hi * NLON, dl, __float_as_int(qw[i0]), 0);
        return;
    }

    const int n   = tile * 64 + lane;
    const bool act = n < NSEG;
    const int nn  = act ? n : (NSEG - 1);

    float xv[64];
    float s = 0.f, s2 = 0.f;
#pragma unroll
    for (int c = 0; c < 64; ++c) { float t = x[c * NSEG + nn]; xv[c] = t; s += t; s2 += t * t; }

    if (grp == 12) {                       // raw x transpose
        for (int ob = 0; ob < 64; ob += 16) {
#pragma unroll
            for (int j = 0; j < 16; ++j) sm[lane * 20 + j] = xv[ob + j];
            __builtin_amdgcn_wave_barrier();
#pragma unroll
            for (int it = 0; it < 4; ++it) {
                int i  = it * 16 + (lane >> 2);
                int j4 = (lane & 3) * 4;
                int np = tile * 64 + i;
                if (np < NSEG)
                    *(float4*)&x_nm[(size_t)np * 64 + ob + j4] = *(const float4*)&sm[i * 20 + j4];
            }
            __builtin_amdgcn_wave_barrier();
        }
        return;
    }

    float mean = s * 0.015625f;
    float var  = s2 * 0.015625f - mean * mean;
    float rstd = rsqrtf(var + 1e-6f);
#pragma unroll
    for (int c = 0; c < 64; ++c) xv[c] = (xv[c] - mean) * rstd * g[c] + b[c];

    const int mm    = grp >> 2;            // 0=q 1=k 2=v
    const int obase = (grp & 3) * 16;
    const float* __restrict__ w = (mm == 0) ? wq : (mm == 1) ? wk : wv;
    float* __restrict__ dst = (mm == 0) ? q_nm : (mm == 1) ? k_nm : v_nm;
    const float scale = (mm == 0) ? 0.25f : 1.0f;   // fold SCALE=1/sqrt(16) into q

#pragma unroll
    for (int j = 0; j < 16; ++j) {
        int o = obase + j;
        float acc = 0.f;
#pragma unroll
        for (int c = 0; c < 64; ++c) acc += w[o * 64 + c] * xv[c];
        sm[lane * 20 + j] = acc * scale;
    }
    __builtin_amdgcn_wave_barrier();
#pragma unroll
    for (int it = 0; it < 4; ++it) {
        int i  = it * 16 + (lane >> 2);
        int j4 = (lane & 3) * 4;
        int np = tile * 64 + i;
        if (np < NSEG)
            *(float4*)&dst[(size_t)np * 64 + obase + j4] = *(const float4*)&sm[i * 20 + j4];
    }
}

// ---------------------------------------------------------------------------
// K2: neighborhood attention, wave per segment, lane = channel. Entries are
// processed serially with wave-uniform index (readfirstlane -> s_load meta,
// SGPR-based k/v row addressing): every global access is one coalesced 256B
// row read. Score via 4-hop shfl_xor reduce in 16-lane head groups; per-lane
// denominator (identical within head group, no reduce). No-max softmax
// (scores O(+-8), exp cannot overflow; ratio identical to reference).
// Fused Wo + residual; writes x1 planar only (out written solely by K3b).
// Pole-heavy rows dispatched first from both grid ends.
// ---------------------------------------------------------------------------
__global__ __launch_bounds__(256) void k2_attn(
    const float* __restrict__ q_nm, const float* __restrict__ k_nm,
    const float* __restrict__ v_nm, const float* __restrict__ x_nm,
    const float* __restrict__ wo,
    const int4* __restrict__ meta,  const int* __restrict__ row_start,
    float* __restrict__ x1_pl)
{
    __shared__ __align__(16) float smatt[4][64];
    __shared__ float smx1[64][5];

    const int tid  = threadIdx.x;
    const int wv   = tid >> 6;
    const int lane = tid & 63;

    // pole-first remap: even blocks count up from seg 0, odd count down
    const int bu   = blockIdx.x >> 1;
    const int seg0 = (blockIdx.x & 1) ? (NSEG - 4 - bu * 4) : (bu * 4);
    const int seg  = seg0 + wv;                    // 4|120 -> same row for block
    const int ho   = seg / NLON;
    const int wlon = __builtin_amdgcn_readfirstlane(seg - ho * NLON);
    int e0 = __builtin_amdgcn_readfirstlane(row_start[ho]);
    int e1 = __builtin_amdgcn_readfirstlane(row_start[ho + 1]);

    const float qreg = q_nm[(size_t)seg * 64 + lane];
    float num = 0.f, den = 0.f;

#pragma unroll 2
    for (int e = e0; e < e1; ++e) {
        int4 mt = meta[e];                         // e wave-uniform -> s_load
        int dlw = mt.y + wlon; if (dlw >= NLON) dlw -= NLON;
        int in  = mt.x + dlw;                      // scalar
        float kd = k_nm[(size_t)in * 64 + lane];   // coalesced 256B row
        float vd = v_nm[(size_t)in * 64 + lane];
        float p  = kd * qreg;
        p += __shfl_xor(p, 1);
        p += __shfl_xor(p, 2);
        p += __shfl_xor(p, 4);
        p += __shfl_xor(p, 8);                     // head-group dot (16 lanes)
        float a = __expf(p) * __int_as_float(mt.z);
        num = fmaf(a, vd, num);
        den += a;
    }

    smatt[wv][lane] = num / den;
    __builtin_amdgcn_wave_barrier();

    // Wo projection: lane = output channel o (wo rows L1-hot, 16 KB total)
    const float4* __restrict__ wr = (const float4*)(wo + lane * 64);
    float acc = 0.f;
#pragma unroll
    for (int c4 = 0; c4 < 16; ++c4) {
        float4 w4 = wr[c4];
        acc += w4.x * smatt[wv][c4 * 4 + 0] + w4.y * smatt[wv][c4 * 4 + 1]
             + w4.z * smatt[wv][c4 * 4 + 2] + w4.w * smatt[wv][c4 * 4 + 3];
    }
    float x1v = acc + x_nm[(size_t)seg * 64 + lane];   // residual, coalesced

    // block transpose for 16B-granular planar store
    smx1[lane][wv] = x1v;
    __syncthreads();
    int c  = tid >> 2;
    int sl = tid & 3;
    x1_pl[c * NSEG + seg0 + sl] = smx1[c][sl];
}

// ---------------------------------------------------------------------------
// K3a: LayerNorm1 + W1 + exact gelu -> m_act planar [128][NSEG].
// grid (115, 4): grp computes 32 hidden units; w1/b1 via SGPR broadcast.
// ---------------------------------------------------------------------------
__global__ __launch_bounds__(64) void k3a_mlp1(
    const float* __restrict__ x1, const float* __restrict__ w1,
    const float* __restrict__ b1, const float* __restrict__ g,
    const float* __restrict__ bb, float* __restrict__ m_act)
{
    const int lane = threadIdx.x;
    const int n    = blockIdx.x * 64 + lane;
    const bool act = n < NSEG;
    const int nn   = act ? n : (NSEG - 1);

    float xv[64];
    float s = 0.f, s2 = 0.f;
#pragma unroll
    for (int c = 0; c < 64; ++c) { float t = x1[c * NSEG + nn]; xv[c] = t; s += t; s2 += t * t; }
    float mean = s * 0.015625f;
    float var  = s2 * 0.015625f - mean * mean;
    float rstd = rsqrtf(var + 1e-6f);
#pragma unroll
    for (int c = 0; c < 64; ++c) xv[c] = (xv[c] - mean) * rstd * g[c] + bb[c];

    const int h0 = blockIdx.y * 32;
    if (!act) return;
#pragma unroll
    for (int j = 0; j < 32; ++j) {
        int h = h0 + j;
        float mh = b1[h];
#pragma unroll
        for (int c = 0; c < 64; ++c) mh += w1[h * 64 + c] * xv[c];
        m_act[h * NSEG + n] = 0.5f * mh * (1.0f + erff(mh * 0.70710678118654752f));
    }
}

// ---------------------------------------------------------------------------
// K3b: out = W2 * m_act + b2 + x1. grid (115, 4): grp handles 16 output
// channels; single non-atomic write of out. w2 via SGPR broadcast.
// ---------------------------------------------------------------------------
__global__ __launch_bounds__(64) void k3b_mlp2(
    const float* __restrict__ m_act, const float* __restrict__ w2,
    const float* __restrict__ b2,    const float* __restrict__ x1,
    float* __restrict__ out)
{
    const int lane = threadIdx.x;
    const int n    = blockIdx.x * 64 + lane;
    if (n >= NSEG) return;
    const int c0   = blockIdx.y * 16;

    float acc[16];
#pragma unroll
    for (int j = 0; j < 16; ++j) acc[j] = 0.f;

    for (int h = 0; h < HIDN; ++h) {
        float mh = m_act[h * NSEG + n];            // coalesced
#pragma unroll
        for (int j = 0; j < 16; ++j) acc[j] += w2[(c0 + j) * HIDN + h] * mh;
    }
#pragma unroll
    for (int j = 0; j < 16; ++j) {
        int c = c0 + j;
        out[c * NSEG + n] = acc[j] + b2[c] + x1[c * NSEG + n];
    }
}

// ---------------------------------------------------------------------------
extern "C" void kernel_launch(void* const* d_in, const int* in_sizes, int n_in,
                              void* d_out, int out_size, void* d_ws, size_t ws_size,
                              hipStream_t stream)
{
    const float* x    = (const float*)d_in[0];
    const float* wq   = (const float*)d_in[1];
    const float* wk   = (const float*)d_in[2];
    const float* wv   = (const float*)d_in[3];
    const float* wo   = (const float*)d_in[4];
    const float* w1   = (const float*)d_in[5];
    const float* b1   = (const float*)d_in[6];
    const float* w2   = (const float*)d_in[7];
    const float* b2   = (const float*)d_in[8];
    const float* ln0g = (const float*)d_in[9];
    const float* ln0b = (const float*)d_in[10];
    const float* ln1g = (const float*)d_in[11];
    const float* ln1b = (const float*)d_in[12];
    const float* qw   = (const float*)d_in[13];
    const int* out_idx = (const int*)d_in[14];
    const int* in_idx  = (const int*)d_in[15];
    float* out = (float*)d_out;

    const int NNZ = in_sizes[15];
    const int E   = NNZ / NLON;
    const size_t N64 = (size_t)NSEG * 64;

    float* ws    = (float*)d_ws;
    float* q_nm  = ws;                    // [NSEG][64], pre-scaled
    float* k_nm  = ws + N64;              // [NSEG][64]
    float* v_nm  = ws + 2 * N64;          // [NSEG][64]
    float* x_nm  = ws + 3 * N64;          // [NSEG][64] raw x (residual)
    float* x1    = ws + 4 * N64;          // [64][NSEG] planar
    float* m_act = ws + 5 * N64;          // [128][NSEG] planar
    int* row_start = (int*)(ws + 7 * N64);            // [62]
    int4* meta = (int4*)(ws + 7 * N64 + 64);          // [E], 16B-aligned

    hipLaunchKernelGGL(k1_ln_qkv, dim3(115, 15), dim3(64), 0, stream,
                       x, wq, wk, wv, ln0g, ln0b, out_idx, in_idx, qw, E,
                       q_nm, k_nm, v_nm, x_nm, row_start, meta);
    hipLaunchKernelGGL(k2_attn, dim3(1830), dim3(256), 0, stream,
                       q_nm, k_nm, v_nm, x_nm, wo, meta, row_start, x1);
    hipLaunchKernelGGL(k3a_mlp1, dim3(115, 4), dim3(64), 0, stream,
                       x1, w1, b1, ln1g, ln1b, m_act);
    hipLaunchKernelGGL(k3b_mlp2, dim3(115, 4), dim3(64), 0, stream,
                       m_act, w2, b2, x1, out);
}

// Round 4
// 329.861 us; speedup vs baseline: 1.0678x; 1.0678x over previous
//
#include <hip/hip_runtime.h>
#include <math.h>

#define NSEG 7320
#define NLON 120
#define HIDN 128

// ---------------------------------------------------------------------------
// K1: grp 0-11: LN0 + QKV projection, planar outputs [64][NSEG] (coalesced
// stores, no LDS). q pre-scaled by 1/sqrt(DH). grp 12-13: meta build
// {hi*120, dl, qw bits, ho} + per-lat-row CSR offsets (grid-stride).
// ---------------------------------------------------------------------------
__global__ __launch_bounds__(64) void k1_ln_qkv(
    const float* __restrict__ x,  const float* __restrict__ wq,
    const float* __restrict__ wk, const float* __restrict__ wv,
    const float* __restrict__ g,  const float* __restrict__ b,
    const int* __restrict__ out_idx, const int* __restrict__ in_idx,
    const float* __restrict__ qw, int E,
    float* __restrict__ q_pl, float* __restrict__ k_pl, float* __restrict__ v_pl,
    int* __restrict__ row_start, int4* __restrict__ meta)
{
    const int lane = threadIdx.x;
    const int tile = blockIdx.x;
    const int grp  = blockIdx.y;

    if (grp >= 12) {                       // meta + row_start build
        for (int e = ((grp - 12) * 115 + tile) * 64 + lane; e < E; e += 2 * 115 * 64) {
            int ho = out_idx[e * NLON] / NLON;
            if (e == 0) {
                row_start[ho] = 0;
            } else {
                int hp = out_idx[(e - 1) * NLON] / NLON;
                if (hp != ho) row_start[ho] = e;
            }
            if (e == E - 1) row_start[ho + 1] = E;
            int i0 = in_idx[e * NLON];     // wo = 0 column: hi*120 + dl
            int hi = i0 / NLON;
            int dl = i0 - hi * NLON;
            meta[e] = make_int4(hi * NLON, dl, __float_as_int(qw[i0]), ho);
        }
        return;
    }

    const int n    = tile * 64 + lane;
    const bool act = n < NSEG;
    const int nn   = act ? n : (NSEG - 1);

    float xv[64];
    float s = 0.f, s2 = 0.f;
#pragma unroll
    for (int c = 0; c < 64; ++c) { float t = x[c * NSEG + nn]; xv[c] = t; s += t; s2 += t * t; }
    float mean = s * 0.015625f;
    float var  = s2 * 0.015625f - mean * mean;
    float rstd = rsqrtf(var + 1e-6f);
#pragma unroll
    for (int c = 0; c < 64; ++c) xv[c] = (xv[c] - mean) * rstd * g[c] + b[c];

    const int mm    = grp >> 2;            // 0=q 1=k 2=v
    const int obase = (grp & 3) * 16;
    const float* __restrict__ w = (mm == 0) ? wq : (mm == 1) ? wk : wv;
    float* __restrict__ dst = (mm == 0) ? q_pl : (mm == 1) ? k_pl : v_pl;
    const float scale = (mm == 0) ? 0.25f : 1.0f;   // fold SCALE=1/sqrt(16) into q

    if (!act) return;
#pragma unroll
    for (int j = 0; j < 16; ++j) {
        int o = obase + j;
        float acc = 0.f;
#pragma unroll
        for (int c = 0; c < 64; ++c) acc += w[o * 64 + c] * xv[c];
        dst[o * NSEG + n] = acc * scale;   // coalesced planar store
    }
}

// ---------------------------------------------------------------------------
// K2a: scores -> alpha[h][e][128]. Block (row ho, 16-entry chunk), 128 thr,
// lane = longitude wo (wo>=120 masked). q row hoisted to 64 VGPRs once; per
// entry: 64 fully-coalesced k loads + 64 fma + 4 exp. No-max softmax (scores
// O(+-8); ratio identical to reference — validated R2/R3).
// ---------------------------------------------------------------------------
__global__ __launch_bounds__(128) void k2a_scores(
    const float* __restrict__ q_pl, const float* __restrict__ k_pl,
    const int4* __restrict__ meta,  const int* __restrict__ row_start,
    float* __restrict__ alpha, int E)
{
    const int wo  = threadIdx.x;           // 0..127
    const bool aw = wo < NLON;
    const int woc = aw ? wo : (NLON - 1);
    const int ho  = blockIdx.x;

    int e0 = __builtin_amdgcn_readfirstlane(row_start[ho]);
    int e1 = __builtin_amdgcn_readfirstlane(row_start[ho + 1]);
    int eb = e0 + blockIdx.y * 16;
    if (eb >= e1) return;
    int ee = eb + 16; if (ee > e1) ee = e1;

    const int segc = ho * NLON + woc;
    float qreg[64];
#pragma unroll
    for (int c = 0; c < 64; ++c) qreg[c] = q_pl[c * NSEG + segc];

    const size_t hstride = ((size_t)E) << 7;
    for (int e = eb; e < ee; ++e) {
        int4 mt = meta[e];
        int dlw = mt.y + woc; if (dlw >= NLON) dlw -= NLON;
        int in  = mt.x + dlw;              // contiguous across lanes (one wrap)
        float s0 = 0.f, s1 = 0.f, s2 = 0.f, s3 = 0.f;
#pragma unroll
        for (int c = 0; c < 16; ++c) s0 += qreg[c]      * k_pl[c * NSEG + in];
#pragma unroll
        for (int c = 0; c < 16; ++c) s1 += qreg[16 + c] * k_pl[(16 + c) * NSEG + in];
#pragma unroll
        for (int c = 0; c < 16; ++c) s2 += qreg[32 + c] * k_pl[(32 + c) * NSEG + in];
#pragma unroll
        for (int c = 0; c < 16; ++c) s3 += qreg[48 + c] * k_pl[(48 + c) * NSEG + in];
        if (aw) {
            float qwv = __int_as_float(mt.z);
            size_t ab = (((size_t)e) << 7) + wo;
            alpha[ab]               = __expf(s0) * qwv;
            alpha[hstride + ab]     = __expf(s1) * qwv;
            alpha[2 * hstride + ab] = __expf(s2) * qwv;
            alpha[3 * hstride + ab] = __expf(s3) * qwv;
        }
    }
}

// ---------------------------------------------------------------------------
// K2b: PV + denominator. Grid (61 rows pole-first, 8, 2 e-splits); 256 thr =
// 4 waves; wave = (c4 group of 4 channels, wo-half). Per entry: 1 alpha + 4 v
// loads (all coalesced) + 5 fma. Denominator is per-lane (per seg,head) —
// no reduction. Writes num_part[split] planar and den_part[split][head].
// ---------------------------------------------------------------------------
__global__ __launch_bounds__(256) void k2b_pv(
    const float* __restrict__ v_pl, const int4* __restrict__ meta,
    const int* __restrict__ row_start, const float* __restrict__ alpha,
    float* __restrict__ num0, float* __restrict__ num1,
    float* __restrict__ den, int E)
{
    const int tid  = threadIdx.x;
    const int wv   = tid >> 6;
    const int lane = tid & 63;
    const int r    = blockIdx.x;
    const int ho   = (r & 1) ? (60 - (r >> 1)) : (r >> 1);   // pole-first
    const int c4   = blockIdx.y * 2 + (wv >> 1);             // 0..15
    const int half = wv & 1;
    const int wo   = half * 64 + lane;
    const bool aw  = wo < NLON;
    const int woc  = aw ? wo : (NLON - 1);
    const int head = c4 >> 2;
    const int c0   = c4 * 4;
    const int spl  = blockIdx.z;

    int e0 = __builtin_amdgcn_readfirstlane(row_start[ho]);
    int e1 = __builtin_amdgcn_readfirstlane(row_start[ho + 1]);
    int em = e0 + ((e1 - e0) >> 1);
    int es = spl ? em : e0;
    int ef = spl ? e1 : em;

    const float* __restrict__ ah = alpha + ((((size_t)head) * E) << 7);
    float n0 = 0.f, n1 = 0.f, n2 = 0.f, n3 = 0.f, d = 0.f;

    for (int e = es; e < ef; ++e) {
        int4 mt = meta[e];
        int dlw = mt.y + woc; if (dlw >= NLON) dlw -= NLON;
        int in  = mt.x + dlw;
        float a = ah[(((size_t)e) << 7) + woc];
        n0 = fmaf(a, v_pl[(c0 + 0) * NSEG + in], n0);
        n1 = fmaf(a, v_pl[(c0 + 1) * NSEG + in], n1);
        n2 = fmaf(a, v_pl[(c0 + 2) * NSEG + in], n2);
        n3 = fmaf(a, v_pl[(c0 + 3) * NSEG + in], n3);
        d += a;
    }

    if (aw) {
        int seg = ho * NLON + wo;
        float* __restrict__ np = spl ? num1 : num0;
        np[(c0 + 0) * NSEG + seg] = n0;
        np[(c0 + 1) * NSEG + seg] = n1;
        np[(c0 + 2) * NSEG + seg] = n2;
        np[(c0 + 3) * NSEG + seg] = n3;
        if ((c4 & 3) == 0) den[(spl * 4 + head) * NSEG + seg] = d;
    }
}

// ---------------------------------------------------------------------------
// K2c: att = (num0+num1)/(den0+den1), Wo projection + residual -> x1 planar.
// grid (115, 8): 8 output channels per group; thread-per-point, all planar.
// ---------------------------------------------------------------------------
__global__ __launch_bounds__(64) void k2c_wo(
    const float* __restrict__ num0, const float* __restrict__ num1,
    const float* __restrict__ den,  const float* __restrict__ wo,
    const float* __restrict__ x,    float* __restrict__ x1)
{
    const int lane = threadIdx.x;
    const int n    = blockIdx.x * 64 + lane;
    if (n >= NSEG) return;

    float rdh[4];
#pragma unroll
    for (int h = 0; h < 4; ++h)
        rdh[h] = 1.0f / (den[h * NSEG + n] + den[(4 + h) * NSEG + n]);

    float att[64];
#pragma unroll
    for (int c = 0; c < 64; ++c)
        att[c] = (num0[c * NSEG + n] + num1[c * NSEG + n]) * rdh[c >> 4];

    const int o0 = blockIdx.y * 8;
#pragma unroll
    for (int j = 0; j < 8; ++j) {
        int o = o0 + j;
        float acc = 0.f;
#pragma unroll
        for (int c = 0; c < 64; ++c) acc += wo[o * 64 + c] * att[c];
        x1[o * NSEG + n] = acc + x[o * NSEG + n];
    }
}

// ---------------------------------------------------------------------------
// K3a: LayerNorm1 + W1 + exact gelu -> m_act planar [128][NSEG].
// grid (115, 8): 16 hidden units per group.
// ---------------------------------------------------------------------------
__global__ __launch_bounds__(64) void k3a_mlp1(
    const float* __restrict__ x1, const float* __restrict__ w1,
    const float* __restrict__ b1, const float* __restrict__ g,
    const float* __restrict__ bb, float* __restrict__ m_act)
{
    const int lane = threadIdx.x;
    const int n    = blockIdx.x * 64 + lane;
    if (n >= NSEG) return;

    float xv[64];
    float s = 0.f, s2 = 0.f;
#pragma unroll
    for (int c = 0; c < 64; ++c) { float t = x1[c * NSEG + n]; xv[c] = t; s += t; s2 += t * t; }
    float mean = s * 0.015625f;
    float var  = s2 * 0.015625f - mean * mean;
    float rstd = rsqrtf(var + 1e-6f);
#pragma unroll
    for (int c = 0; c < 64; ++c) xv[c] = (xv[c] - mean) * rstd * g[c] + bb[c];

    const int h0 = blockIdx.y * 16;
#pragma unroll
    for (int j = 0; j < 16; ++j) {
        int h = h0 + j;
        float mh = b1[h];
#pragma unroll
        for (int c = 0; c < 64; ++c) mh += w1[h * 64 + c] * xv[c];
        m_act[h * NSEG + n] = 0.5f * mh * (1.0f + erff(mh * 0.70710678118654752f));
    }
}

// ---------------------------------------------------------------------------
// K3b: out = W2 * m_act + b2 + x1. grid (115, 8): 8 output channels/group.
// ---------------------------------------------------------------------------
__global__ __launch_bounds__(64) void k3b_mlp2(
    const float* __restrict__ m_act, const float* __restrict__ w2,
    const float* __restrict__ b2,    const float* __restrict__ x1,
    float* __restrict__ out)
{
    const int lane = threadIdx.x;
    const int n    = blockIdx.x * 64 + lane;
    if (n >= NSEG) return;
    const int c0   = blockIdx.y * 8;

    float acc[8];
#pragma unroll
    for (int j = 0; j < 8; ++j) acc[j] = 0.f;

    for (int h = 0; h < HIDN; ++h) {
        float mh = m_act[h * NSEG + n];    // coalesced
#pragma unroll
        for (int j = 0; j < 8; ++j) acc[j] += w2[(c0 + j) * HIDN + h] * mh;
    }
#pragma unroll
    for (int j = 0; j < 8; ++j) {
        int c = c0 + j;
        out[c * NSEG + n] = acc[j] + b2[c] + x1[c * NSEG + n];
    }
}

// ---------------------------------------------------------------------------
extern "C" void kernel_launch(void* const* d_in, const int* in_sizes, int n_in,
                              void* d_out, int out_size, void* d_ws, size_t ws_size,
                              hipStream_t stream)
{
    const float* x    = (const float*)d_in[0];
    const float* wq   = (const float*)d_in[1];
    const float* wk   = (const float*)d_in[2];
    const float* wv   = (const float*)d_in[3];
    const float* wo   = (const float*)d_in[4];
    const float* w1   = (const float*)d_in[5];
    const float* b1   = (const float*)d_in[6];
    const float* w2   = (const float*)d_in[7];
    const float* b2   = (const float*)d_in[8];
    const float* ln0g = (const float*)d_in[9];
    const float* ln0b = (const float*)d_in[10];
    const float* ln1g = (const float*)d_in[11];
    const float* ln1b = (const float*)d_in[12];
    const float* qw   = (const float*)d_in[13];
    const int* out_idx = (const int*)d_in[14];
    const int* in_idx  = (const int*)d_in[15];
    float* out = (float*)d_out;

    const int NNZ = in_sizes[15];
    const int E   = NNZ / NLON;
    const size_t N64 = (size_t)NSEG * 64;

    float* ws    = (float*)d_ws;
    float* q_pl  = ws;                     // [64][NSEG]
    float* k_pl  = ws + N64;
    float* v_pl  = ws + 2 * N64;
    float* num0  = ws + 3 * N64;
    float* num1  = ws + 4 * N64;
    float* x1    = ws + 5 * N64;
    float* m_act = ws + 6 * N64;           // [128][NSEG] = 2*N64
    float* den   = ws + 8 * N64;           // [8][NSEG]
    int*   row_start = (int*)(ws + 8 * N64 + 8 * NSEG);       // [62]
    int4*  meta  = (int4*)(ws + 8 * N64 + 8 * NSEG + 64);     // [E]
    float* alpha = ws + 8 * N64 + 8 * NSEG + 64 + 4 * (size_t)E;  // [4][E][128]

    hipLaunchKernelGGL(k1_ln_qkv, dim3(115, 14), dim3(64), 0, stream,
                       x, wq, wk, wv, ln0g, ln0b, out_idx, in_idx, qw, E,
                       q_pl, k_pl, v_pl, row_start, meta);
    hipLaunchKernelGGL(k2a_scores, dim3(61, 48), dim3(128), 0, stream,
                       q_pl, k_pl, meta, row_start, alpha, E);
    hipLaunchKernelGGL(k2b_pv, dim3(61, 8, 2), dim3(256), 0, stream,
                       v_pl, meta, row_start, alpha, num0, num1, den, E);
    hipLaunchKernelGGL(k2c_wo, dim3(115, 8), dim3(64), 0, stream,
                       num0, num1, den, wo, x, x1);
    hipLaunchKernelGGL(k3a_mlp1, dim3(115, 8), dim3(64), 0, stream,
                       x1, w1, b1, ln1g, ln1b, m_act);
    hipLaunchKernelGGL(k3b_mlp2, dim3(115, 8), dim3(64), 0, stream,
                       m_act, w2, b2, x1, out);
}

// Round 6
// 222.436 us; speedup vs baseline: 1.5835x; 1.4829x over previous
//
#include <hip/hip_runtime.h>
#include <math.h>

#define NSEG 7320
#define NLON 120
#define HIDN 128
#define ZSPL 6
#define ECHUNK 8
#define NCHUNK 96   // 96*8 = 768-entry cap per row (max row ~520; R4-proven)

// ---------------------------------------------------------------------------
// Z0: zero num[64][NSEG] + den[4][NSEG] (contiguous 68*NSEG floats).
// ---------------------------------------------------------------------------
__global__ __launch_bounds__(256) void z0_zero(float4* __restrict__ p, int n4)
{
    int i = blockIdx.x * 256 + threadIdx.x;
    if (i < n4) p[i] = make_float4(0.f, 0.f, 0.f, 0.f);
}

// ---------------------------------------------------------------------------
// K1: grp 0-23: LN0 + QKV projection (8 output channels per group), planar
// [64][NSEG] outputs, coalesced. q pre-scaled by 1/sqrt(DH)=0.25.
// grp 24: meta {hi*120, dl, qw bits, ho} + per-lat-row CSR offsets.
// ---------------------------------------------------------------------------
__global__ __launch_bounds__(64) void k1_ln_qkv(
    const float* __restrict__ x,  const float* __restrict__ wq,
    const float* __restrict__ wk, const float* __restrict__ wv,
    const float* __restrict__ g,  const float* __restrict__ b,
    const int* __restrict__ out_idx, const int* __restrict__ in_idx,
    const float* __restrict__ qw, int E,
    float* __restrict__ q_pl, float* __restrict__ k_pl, float* __restrict__ v_pl,
    int* __restrict__ row_start, int4* __restrict__ meta)
{
    const int lane = threadIdx.x;
    const int tile = blockIdx.x;
    const int grp  = blockIdx.y;

    if (grp >= 24) {                       // meta + row_start build
        for (int e = tile * 64 + lane; e < E; e += 115 * 64) {
            int ho = out_idx[e * NLON] / NLON;
            if (e == 0) {
                row_start[ho] = 0;
            } else {
                int hp = out_idx[(e - 1) * NLON] / NLON;
                if (hp != ho) row_start[ho] = e;
            }
            if (e == E - 1) row_start[ho + 1] = E;
            int i0 = in_idx[e * NLON];     // wo = 0 column: hi*120 + dl
            int hi = i0 / NLON;
            int dl = i0 - hi * NLON;
            meta[e] = make_int4(hi * NLON, dl, __float_as_int(qw[i0]), ho);
        }
        return;
    }

    const int n = tile * 64 + lane;
    if (n >= NSEG) return;

    float xv[64];
    float s = 0.f, s2 = 0.f;
#pragma unroll
    for (int c = 0; c < 64; ++c) { float t = x[c * NSEG + n]; xv[c] = t; s += t; s2 += t * t; }
    float mean = s * 0.015625f;
    float var  = s2 * 0.015625f - mean * mean;
    float rstd = rsqrtf(var + 1e-6f);
#pragma unroll
    for (int c = 0; c < 64; ++c) xv[c] = (xv[c] - mean) * rstd * g[c] + b[c];

    const int mm    = grp >> 3;            // 0=q 1=k 2=v
    const int obase = (grp & 7) * 8;
    const float* __restrict__ w = (mm == 0) ? wq : (mm == 1) ? wk : wv;
    float* __restrict__ dst = (mm == 0) ? q_pl : (mm == 1) ? k_pl : v_pl;
    const float scale = (mm == 0) ? 0.25f : 1.0f;

#pragma unroll
    for (int j = 0; j < 8; ++j) {
        int o = obase + j;
        float acc = 0.f;
#pragma unroll
        for (int c = 0; c < 64; ++c) acc += w[o * 64 + c] * xv[c];
        dst[o * NSEG + n] = acc * scale;
    }
}

// ---------------------------------------------------------------------------
// K2a: scores -> alpha[h][e][128] + den atomics. Block (row, ECHUNK-entry
// chunk), 128 thr, lane = wo. q row hoisted to 64 VGPRs; per entry 64
// coalesced k loads + 64 fma + 4 exp. den accumulated in registers over the
// chunk, one atomicAdd per head per lane. No-max softmax (scores O(+-8)).
// Grid y = NCHUNK (cap 768 entries/row; max row ~520) with early exit.
// ---------------------------------------------------------------------------
__global__ __launch_bounds__(128) void k2a_scores(
    const float* __restrict__ q_pl, const float* __restrict__ k_pl,
    const int4* __restrict__ meta,  const int* __restrict__ row_start,
    float* __restrict__ alpha, float* __restrict__ den, int E)
{
    const int wo  = threadIdx.x;           // 0..127
    const bool aw = wo < NLON;
    const int woc = aw ? wo : (NLON - 1);
    const int ho  = blockIdx.x;

    int e0 = __builtin_amdgcn_readfirstlane(row_start[ho]);
    int e1 = __builtin_amdgcn_readfirstlane(row_start[ho + 1]);
    int eb = e0 + blockIdx.y * ECHUNK;
    if (eb >= e1) return;
    int ee = eb + ECHUNK; if (ee > e1) ee = e1;

    const int segc = ho * NLON + woc;
    float qreg[64];
#pragma unroll
    for (int c = 0; c < 64; ++c) qreg[c] = q_pl[c * NSEG + segc];

    const size_t hstride = ((size_t)E) << 7;
    float dh0 = 0.f, dh1 = 0.f, dh2 = 0.f, dh3 = 0.f;

    for (int e = eb; e < ee; ++e) {
        int4 mt = meta[e];
        int dlw = mt.y + woc; if (dlw >= NLON) dlw -= NLON;
        int in  = mt.x + dlw;              // contiguous across lanes
        float s0 = 0.f, s1 = 0.f, s2 = 0.f, s3 = 0.f;
#pragma unroll
        for (int c = 0; c < 16; ++c) s0 += qreg[c]      * k_pl[c * NSEG + in];
#pragma unroll
        for (int c = 0; c < 16; ++c) s1 += qreg[16 + c] * k_pl[(16 + c) * NSEG + in];
#pragma unroll
        for (int c = 0; c < 16; ++c) s2 += qreg[32 + c] * k_pl[(32 + c) * NSEG + in];
#pragma unroll
        for (int c = 0; c < 16; ++c) s3 += qreg[48 + c] * k_pl[(48 + c) * NSEG + in];
        float qwv = aw ? __int_as_float(mt.z) : 0.f;
        float a0 = __expf(s0) * qwv, a1 = __expf(s1) * qwv;
        float a2 = __expf(s2) * qwv, a3 = __expf(s3) * qwv;
        dh0 += a0; dh1 += a1; dh2 += a2; dh3 += a3;
        if (aw) {
            size_t ab = (((size_t)e) << 7) + wo;
            alpha[ab]               = a0;
            alpha[hstride + ab]     = a1;
            alpha[2 * hstride + ab] = a2;
            alpha[3 * hstride + ab] = a3;
        }
    }
    if (aw) {
        int seg = ho * NLON + wo;
        atomicAdd(&den[0 * NSEG + seg], dh0);
        atomicAdd(&den[1 * NSEG + seg], dh1);
        atomicAdd(&den[2 * NSEG + seg], dh2);
        atomicAdd(&den[3 * NSEG + seg], dh3);
    }
}

// ---------------------------------------------------------------------------
// K2b: PV. Grid (61 rows pole-first, 8, ZSPL e-splits); 256 thr = 4 waves;
// wave = (c4 group of 4 channels, wo-half). Inner loop manually unrolled 4x:
// 20 independent coalesced loads in flight per batch. Register partials,
// merged with 4 atomicAdds/lane.
// ---------------------------------------------------------------------------
__global__ __launch_bounds__(256) void k2b_pv(
    const float* __restrict__ v_pl, const int4* __restrict__ meta,
    const int* __restrict__ row_start, const float* __restrict__ alpha,
    float* __restrict__ num, int E)
{
    const int tid  = threadIdx.x;
    const int wv   = tid >> 6;
    const int lane = tid & 63;
    const int r    = blockIdx.x;
    const int ho   = (r & 1) ? (60 - (r >> 1)) : (r >> 1);   // pole-first
    const int c4   = blockIdx.y * 2 + (wv >> 1);             // 0..15
    const int half = wv & 1;
    const int wo   = half * 64 + lane;
    const bool aw  = wo < NLON;
    const int woc  = aw ? wo : (NLON - 1);
    const int head = c4 >> 2;
    const int c0   = c4 * 4;

    int e0 = __builtin_amdgcn_readfirstlane(row_start[ho]);
    int e1 = __builtin_amdgcn_readfirstlane(row_start[ho + 1]);
    int len = e1 - e0;
    int es = e0 + (len * (int)blockIdx.z) / ZSPL;
    int ef = e0 + (len * ((int)blockIdx.z + 1)) / ZSPL;

    const float* __restrict__ ah = alpha + ((((size_t)head) * E) << 7);
    const float* __restrict__ v0 = v_pl + (size_t)(c0 + 0) * NSEG;
    const float* __restrict__ v1 = v_pl + (size_t)(c0 + 1) * NSEG;
    const float* __restrict__ v2 = v_pl + (size_t)(c0 + 2) * NSEG;
    const float* __restrict__ v3 = v_pl + (size_t)(c0 + 3) * NSEG;

    float n0 = 0.f, n1 = 0.f, n2 = 0.f, n3 = 0.f;

    int e = es;
    for (; e + 4 <= ef; e += 4) {
        int4 ma = meta[e], mb = meta[e + 1], mc = meta[e + 2], md = meta[e + 3];
        int da = ma.y + woc; if (da >= NLON) da -= NLON;
        int db = mb.y + woc; if (db >= NLON) db -= NLON;
        int dc = mc.y + woc; if (dc >= NLON) dc -= NLON;
        int dd = md.y + woc; if (dd >= NLON) dd -= NLON;
        int ia = ma.x + da, ib = mb.x + db, ic = mc.x + dc, id = md.x + dd;
        float aa = ah[(((size_t)(e + 0)) << 7) + woc];
        float ab = ah[(((size_t)(e + 1)) << 7) + woc];
        float ac = ah[(((size_t)(e + 2)) << 7) + woc];
        float ad = ah[(((size_t)(e + 3)) << 7) + woc];
        float va0 = v0[ia], va1 = v1[ia], va2 = v2[ia], va3 = v3[ia];
        float vb0 = v0[ib], vb1 = v1[ib], vb2 = v2[ib], vb3 = v3[ib];
        float vc0 = v0[ic], vc1 = v1[ic], vc2 = v2[ic], vc3 = v3[ic];
        float vd0 = v0[id], vd1 = v1[id], vd2 = v2[id], vd3 = v3[id];
        n0 = fmaf(aa, va0, n0); n1 = fmaf(aa, va1, n1);
        n2 = fmaf(aa, va2, n2); n3 = fmaf(aa, va3, n3);
        n0 = fmaf(ab, vb0, n0); n1 = fmaf(ab, vb1, n1);
        n2 = fmaf(ab, vb2, n2); n3 = fmaf(ab, vb3, n3);
        n0 = fmaf(ac, vc0, n0); n1 = fmaf(ac, vc1, n1);
        n2 = fmaf(ac, vc2, n2); n3 = fmaf(ac, vc3, n3);
        n0 = fmaf(ad, vd0, n0); n1 = fmaf(ad, vd1, n1);
        n2 = fmaf(ad, vd2, n2); n3 = fmaf(ad, vd3, n3);
    }
    for (; e < ef; ++e) {
        int4 mt = meta[e];
        int dlw = mt.y + woc; if (dlw >= NLON) dlw -= NLON;
        int in  = mt.x + dlw;
        float a = ah[(((size_t)e) << 7) + woc];
        n0 = fmaf(a, v0[in], n0); n1 = fmaf(a, v1[in], n1);
        n2 = fmaf(a, v2[in], n2); n3 = fmaf(a, v3[in], n3);
    }

    if (aw) {
        int seg = ho * NLON + wo;
        atomicAdd(&num[(c0 + 0) * NSEG + seg], n0);
        atomicAdd(&num[(c0 + 1) * NSEG + seg], n1);
        atomicAdd(&num[(c0 + 2) * NSEG + seg], n2);
        atomicAdd(&num[(c0 + 3) * NSEG + seg], n3);
    }
}

// ---------------------------------------------------------------------------
// K2c: att = num/den, Wo projection + residual -> x1 planar.
// grid (115, 8): 8 output channels per group; thread-per-point, all planar.
// ---------------------------------------------------------------------------
__global__ __launch_bounds__(64) void k2c_wo(
    const float* __restrict__ num, const float* __restrict__ den,
    const float* __restrict__ wo,  const float* __restrict__ x,
    float* __restrict__ x1)
{
    const int lane = threadIdx.x;
    const int n    = blockIdx.x * 64 + lane;
    if (n >= NSEG) return;

    float rdh[4];
#pragma unroll
    for (int h = 0; h < 4; ++h) rdh[h] = 1.0f / den[h * NSEG + n];

    float att[64];
#pragma unroll
    for (int c = 0; c < 64; ++c) att[c] = num[c * NSEG + n] * rdh[c >> 4];

    const int o0 = blockIdx.y * 8;
#pragma unroll
    for (int j = 0; j < 8; ++j) {
        int o = o0 + j;
        float acc = 0.f;
#pragma unroll
        for (int c = 0; c < 64; ++c) acc += wo[o * 64 + c] * att[c];
        x1[o * NSEG + n] = acc + x[o * NSEG + n];
    }
}

// ---------------------------------------------------------------------------
// K3a: LayerNorm1 + W1 + exact gelu -> m_act planar [128][NSEG].
// grid (115, 8): 16 hidden units per group.
// ---------------------------------------------------------------------------
__global__ __launch_bounds__(64) void k3a_mlp1(
    const float* __restrict__ x1, const float* __restrict__ w1,
    const float* __restrict__ b1, const float* __restrict__ g,
    const float* __restrict__ bb, float* __restrict__ m_act)
{
    const int lane = threadIdx.x;
    const int n    = blockIdx.x * 64 + lane;
    if (n >= NSEG) return;

    float xv[64];
    float s = 0.f, s2 = 0.f;
#pragma unroll
    for (int c = 0; c < 64; ++c) { float t = x1[c * NSEG + n]; xv[c] = t; s += t; s2 += t * t; }
    float mean = s * 0.015625f;
    float var  = s2 * 0.015625f - mean * mean;
    float rstd = rsqrtf(var + 1e-6f);
#pragma unroll
    for (int c = 0; c < 64; ++c) xv[c] = (xv[c] - mean) * rstd * g[c] + bb[c];

    const int h0 = blockIdx.y * 16;
#pragma unroll
    for (int j = 0; j < 16; ++j) {
        int h = h0 + j;
        float mh = b1[h];
#pragma unroll
        for (int c = 0; c < 64; ++c) mh += w1[h * 64 + c] * xv[c];
        m_act[h * NSEG + n] = 0.5f * mh * (1.0f + erff(mh * 0.70710678118654752f));
    }
}

// ---------------------------------------------------------------------------
// K3b: out = W2 * m_act + b2 + x1. grid (115, 8): 8 output channels/group.
// ---------------------------------------------------------------------------
__global__ __launch_bounds__(64) void k3b_mlp2(
    const float* __restrict__ m_act, const float* __restrict__ w2,
    const float* __restrict__ b2,    const float* __restrict__ x1,
    float* __restrict__ out)
{
    const int lane = threadIdx.x;
    const int n    = blockIdx.x * 64 + lane;
    if (n >= NSEG) return;
    const int c0   = blockIdx.y * 8;

    float acc[8];
#pragma unroll
    for (int j = 0; j < 8; ++j) acc[j] = 0.f;

#pragma unroll 8
    for (int h = 0; h < HIDN; ++h) {
        float mh = m_act[h * NSEG + n];
#pragma unroll
        for (int j = 0; j < 8; ++j) acc[j] += w2[(c0 + j) * HIDN + h] * mh;
    }
#pragma unroll
    for (int j = 0; j < 8; ++j) {
        int c = c0 + j;
        out[c * NSEG + n] = acc[j] + b2[c] + x1[c * NSEG + n];
    }
}

// ---------------------------------------------------------------------------
extern "C" void kernel_launch(void* const* d_in, const int* in_sizes, int n_in,
                              void* d_out, int out_size, void* d_ws, size_t ws_size,
                              hipStream_t stream)
{
    const float* x    = (const float*)d_in[0];
    const float* wq   = (const float*)d_in[1];
    const float* wk   = (const float*)d_in[2];
    const float* wv   = (const float*)d_in[3];
    const float* wo   = (const float*)d_in[4];
    const float* w1   = (const float*)d_in[5];
    const float* b1   = (const float*)d_in[6];
    const float* w2   = (const float*)d_in[7];
    const float* b2   = (const float*)d_in[8];
    const float* ln0g = (const float*)d_in[9];
    const float* ln0b = (const float*)d_in[10];
    const float* ln1g = (const float*)d_in[11];
    const float* ln1b = (const float*)d_in[12];
    const float* qw   = (const float*)d_in[13];
    const int* out_idx = (const int*)d_in[14];
    const int* in_idx  = (const int*)d_in[15];
    float* out = (float*)d_out;

    const int NNZ = in_sizes[15];
    const int E   = NNZ / NLON;
    const size_t N64 = (size_t)NSEG * 64;

    float* ws    = (float*)d_ws;
    float* q_pl  = ws;                     // [64][NSEG]
    float* k_pl  = ws + N64;
    float* v_pl  = ws + 2 * N64;
    float* num   = ws + 3 * N64;           // [64][NSEG]  (zeroed)
    float* den   = ws + 4 * N64;           // [4][NSEG]   (zeroed, contiguous w/ num)
    float* x1    = ws + 4 * N64 + 4 * NSEG;
    float* m_act = ws + 5 * N64 + 4 * NSEG;           // [128][NSEG]
    int*   row_start = (int*)(ws + 7 * N64 + 4 * NSEG);            // [62]
    int4*  meta  = (int4*)(ws + 7 * N64 + 4 * NSEG + 64);          // [E]
    float* alpha = ws + 7 * N64 + 4 * NSEG + 64 + 4 * (size_t)E;   // [4][E][128]

    const int nz4 = (int)((68 * NSEG) / 4);
    hipLaunchKernelGGL(z0_zero, dim3((nz4 + 255) / 256), dim3(256), 0, stream,
                       (float4*)num, nz4);
    hipLaunchKernelGGL(k1_ln_qkv, dim3(115, 25), dim3(64), 0, stream,
                       x, wq, wk, wv, ln0g, ln0b, out_idx, in_idx, qw, E,
                       q_pl, k_pl, v_pl, row_start, meta);
    hipLaunchKernelGGL(k2a_scores, dim3(61, NCHUNK), dim3(128), 0, stream,
                       q_pl, k_pl, meta, row_start, alpha, den, E);
    hipLaunchKernelGGL(k2b_pv, dim3(61, 8, ZSPL), dim3(256), 0, stream,
                       v_pl, meta, row_start, alpha, num, E);
    hipLaunchKernelGGL(k2c_wo, dim3(115, 8), dim3(64), 0, stream,
                       num, den, wo, x, x1);
    hipLaunchKernelGGL(k3a_mlp1, dim3(115, 8), dim3(64), 0, stream,
                       x1, w1, b1, ln1g, ln1b, m_act);
    hipLaunchKernelGGL(k3b_mlp2, dim3(115, 8), dim3(64), 0, stream,
                       m_act, w2, b2, x1, out);
}